// Round 3
// baseline (21116.893 us; speedup 1.0000x reference)
//
#include <hip/hip_runtime.h>
#include <hip/hip_bf16.h>

#define MDIM 512
#define NDIM 1024
#define MAX_OUTER 200
#define X_INNER 20
#define RHO 1.0f
#define XSTEP 1e-3f

#define GBLK 32
#define TPB 256
#define NPER (NDIM / GBLK) /* 32 x-rows per block */
#define MPER (MDIM / GBLK) /* 16 s/u-rows per block */

// ---------------- cross-block memory ops (bypass non-coherent L1/L2) -------

__device__ __forceinline__ float agent_load(const float* p) {
  return __hip_atomic_load(p, __ATOMIC_RELAXED, __HIP_MEMORY_SCOPE_AGENT);
}
__device__ __forceinline__ void agent_store(float* p, float v) {
  __hip_atomic_store(p, v, __ATOMIC_RELAXED, __HIP_MEMORY_SCOPE_AGENT);
}

__device__ __forceinline__ float wave_reduce_sum(float v) {
#pragma unroll
  for (int off = 32; off > 0; off >>= 1) v += __shfl_xor(v, off, 64);
  return v;
}

// Distributed-flag grid barrier. Data written before this barrier must use
// agent_store (goes to LLC); data read after must use agent_load. Flags use
// release/acquire for ordering. All GBLK blocks are co-resident (32 << 256 CU).
__device__ __forceinline__ void grid_barrier(int* flags, int epoch, int bid) {
  __syncthreads();  // all this block's agent stores issued + vmcnt drained
  if (threadIdx.x == 0)
    __hip_atomic_store(&flags[bid * 32], epoch, __ATOMIC_RELEASE,
                       __HIP_MEMORY_SCOPE_AGENT);
  if (threadIdx.x < GBLK) {
    while (__hip_atomic_load(&flags[threadIdx.x * 32], __ATOMIC_ACQUIRE,
                             __HIP_MEMORY_SCOPE_AGENT) < epoch)
      __builtin_amdgcn_s_sleep(2);
  }
  __syncthreads();
}

// ---------------- kernel 1: M = A^T A  (1024x1024 f32) ----------------

#define ATA_BK 32
#define ATA_BT 64

__global__ void __launch_bounds__(256) ata_kernel(const float* __restrict__ A,
                                                  float* __restrict__ Mout) {
  __shared__ float As[ATA_BK][ATA_BT];
  __shared__ float Bs[ATA_BK][ATA_BT];
  const int bi = blockIdx.y * ATA_BT;
  const int bj = blockIdx.x * ATA_BT;
  const int tid = threadIdx.x;
  const int tx = tid & 15, ty = tid >> 4;
  float acc[4][4] = {};
  for (int k0 = 0; k0 < MDIM; k0 += ATA_BK) {
#pragma unroll
    for (int t = tid; t < ATA_BK * ATA_BT; t += 256) {
      int kk = t >> 6, ii = t & 63;
      As[kk][ii] = A[(size_t)(k0 + kk) * NDIM + bi + ii];
      Bs[kk][ii] = A[(size_t)(k0 + kk) * NDIM + bj + ii];
    }
    __syncthreads();
#pragma unroll
    for (int kk = 0; kk < ATA_BK; ++kk) {
      float a[4], bb[4];
#pragma unroll
      for (int r = 0; r < 4; ++r) a[r] = As[kk][ty * 4 + r];
#pragma unroll
      for (int r = 0; r < 4; ++r) bb[r] = Bs[kk][tx * 4 + r];
#pragma unroll
      for (int r = 0; r < 4; ++r)
#pragma unroll
        for (int q = 0; q < 4; ++q) acc[r][q] = fmaf(a[r], bb[q], acc[r][q]);
    }
    __syncthreads();
  }
#pragma unroll
  for (int r = 0; r < 4; ++r)
#pragma unroll
    for (int q = 0; q < 4; ++q)
      Mout[(size_t)(bi + ty * 4 + r) * NDIM + bj + tx * 4 + q] = acc[r][q];
}

// ---------------- kernel 2: persistent ADMM loop ----------------

__global__ void __launch_bounds__(TPB) admm_kernel(
    const float* __restrict__ A, const float* __restrict__ bvec,
    const float* __restrict__ cvec, const float* __restrict__ Mm,
    float* __restrict__ xg0, float* __restrict__ xg1, float* __restrict__ sg,
    float* __restrict__ ug, int* flags, float* __restrict__ out) {
  __shared__ float xs[NDIM];       // full current x (block-local staged copy)
  __shared__ float rs[MDIM];       // r = s + b - u (reused for u at the end)
  __shared__ float wl[NPER];       // block's slice of w = A^T r
  __shared__ float cl[NPER];       // block's slice of c
  __shared__ float wred[NPER][9];  // reduction scratch (padded)

  const int tid = threadIdx.x;
  const int bid = blockIdx.x;
  const int wave = tid >> 6;
  const int lane = tid & 63;
  const int i0 = bid * NPER;  // x/w/nu row offset
  const int k0 = bid * MPER;  // s/u/lambda row offset

  float* xbuf[2] = {xg0, xg1};
  int p = 0;  // xbuf[p] holds current x (both zeroed by memset; x0 = 0)

  if (tid < NPER) cl[tid] = cvec[i0 + tid];
  for (int j = tid; j < NDIM; j += TPB) xs[j] = 0.0f;
  __syncthreads();

  int epoch = 0;

  for (int outer = 0; outer < MAX_OUTER; ++outer) {
    // ---- w-phase: w[i] = sum_k A[k][i] * (s[k]+b[k]-u[k]) for block's i ----
    for (int k = tid; k < MDIM; k += TPB)
      rs[k] = agent_load(&sg[k]) + bvec[k] - agent_load(&ug[k]);
    __syncthreads();
    {
      const int ii = tid & (NPER - 1);
      const int kg = tid >> 5;  // 0..7
      float pp = 0.0f;
#pragma unroll
      for (int kk = 0; kk < MDIM / 8; ++kk) {
        const int k = kg * (MDIM / 8) + kk;
        pp = fmaf(A[(size_t)k * NDIM + i0 + ii], rs[k], pp);
      }
      wred[ii][kg] = pp;
    }
    __syncthreads();
    if (tid < NPER) {
      float sum = 0.0f;
#pragma unroll
      for (int q = 0; q < 8; ++q) sum += wred[tid][q];
      wl[tid] = sum;
    }
    __syncthreads();

    // ---- inner loop: x <- max(x - eta*(c + rho*(Mx - w)), 0), dbl-buffered --
    for (int it = 0; it < X_INNER; ++it) {
      float* xnew = xbuf[p ^ 1];
#pragma unroll
      for (int rr = 0; rr < 8; ++rr) {
        const int ii = wave * 8 + rr;
        const int i = i0 + ii;
        const float* Mrow = Mm + (size_t)i * NDIM;
        float pp = 0.0f;
#pragma unroll
        for (int t = 0; t < NDIM / 64; ++t) {
          const int j = lane + t * 64;
          pp = fmaf(Mrow[j], xs[j], pp);
        }
        pp = wave_reduce_sum(pp);
        if (lane == 0) {
          const float g = cl[ii] + RHO * (pp - wl[ii]);
          agent_store(&xnew[i], fmaxf(xs[i] - XSTEP * g, 0.0f));
        }
      }
      ++epoch;
      grid_barrier(flags, epoch, bid);
      for (int j = tid; j < NDIM; j += TPB) xs[j] = agent_load(&xnew[j]);
      p ^= 1;
      __syncthreads();
    }

    // ---- Ax-phase: s,u update for block's k-slice ----
#pragma unroll
    for (int rr = 0; rr < 4; ++rr) {
      const int k = k0 + wave * 4 + rr;
      const float* Arow = A + (size_t)k * NDIM;
      float pp = 0.0f;
#pragma unroll
      for (int t = 0; t < NDIM / 64; ++t) {
        const int j = lane + t * 64;
        pp = fmaf(Arow[j], xs[j], pp);
      }
      pp = wave_reduce_sum(pp);
      if (lane == 0) {
        const float uk = agent_load(&ug[k]);
        const float bk = bvec[k];
        const float sv = fmaxf(pp - bk + uk, 0.0f);
        agent_store(&sg[k], sv);
        agent_store(&ug[k], uk + pp - sv - bk);
      }
    }
    ++epoch;
    grid_barrier(flags, epoch, bid);
  }

  // ---- final outputs: [x | s | u | lambda | nu] as f32 (ref dtype) ----
  if (tid < NPER) out[i0 + tid] = xs[i0 + tid];
  if (tid < MPER) {
    const int k = k0 + tid;
    const float sv = agent_load(&sg[k]);
    const float uv = agent_load(&ug[k]);
    out[NDIM + k] = sv;
    out[NDIM + MDIM + k] = uv;
    out[NDIM + 2 * MDIM + k] = fmaxf(-RHO * uv, 0.0f);
  }
  // nu = max(c + A^T (rho*u), 0) for block's i-slice
  for (int k = tid; k < MDIM; k += TPB) rs[k] = agent_load(&ug[k]);
  __syncthreads();
  {
    const int ii = tid & (NPER - 1);
    const int kg = tid >> 5;
    float pp = 0.0f;
#pragma unroll
    for (int kk = 0; kk < MDIM / 8; ++kk) {
      const int k = kg * (MDIM / 8) + kk;
      pp = fmaf(A[(size_t)k * NDIM + i0 + ii], rs[k], pp);
    }
    wred[ii][kg] = pp;
  }
  __syncthreads();
  if (tid < NPER) {
    float t = 0.0f;
#pragma unroll
    for (int q = 0; q < 8; ++q) t += wred[tid][q];
    out[NDIM + 3 * MDIM + i0 + tid] = fmaxf(cl[tid] + RHO * t, 0.0f);
  }
}

// ---------------- host ----------------

extern "C" void kernel_launch(void* const* d_in, const int* in_sizes, int n_in,
                              void* d_out, int out_size, void* d_ws,
                              size_t ws_size, hipStream_t stream) {
  const float* A = (const float*)d_in[0];
  const float* b = (const float*)d_in[1];
  const float* c = (const float*)d_in[2];
  float* out = (float*)d_out;

  float* Mws = (float*)d_ws;              // 1024*1024 f32 = 4 MB
  float* xg0 = Mws + (size_t)NDIM * NDIM; // 1024 (x buffer, parity 0)
  float* xg1 = xg0 + NDIM;                // 1024 (x buffer, parity 1)
  float* sg = xg1 + NDIM;                 // 512
  float* ug = sg + MDIM;                  // 512
  int* flags = (int*)(ug + MDIM);         // GBLK * 32 ints

  // zero x (both buffers), s, u, and barrier flags (ws is poisoned 0xAA)
  hipMemsetAsync(xg0, 0,
                 (2 * NDIM + 2 * MDIM) * sizeof(float) +
                     GBLK * 32 * sizeof(int),
                 stream);

  dim3 g1(NDIM / ATA_BT, NDIM / ATA_BT);
  ata_kernel<<<g1, 256, 0, stream>>>(A, Mws);
  admm_kernel<<<GBLK, TPB, 0, stream>>>(A, b, c, Mws, xg0, xg1, sg, ug, flags,
                                        out);
}